// Round 1
// baseline (158.732 us; speedup 1.0000x reference)
//
#include <hip/hip_runtime.h>

// Bit-serial SAR ADC quantizer.
// Outputs concatenated in d_out: q [8192*1024] f32, Q [8192*1024*8] f32 (bit innermost), W [36] f32.

constexpr int NB     = 8;
constexpr int TOTAL  = 8192 * 1024;        // LENGTH * PACKET
constexpr int NVEC   = TOTAL / 4;          // float4 groups
constexpr int Q_OFF  = TOTAL;              // start of Q region (elements)
constexpr int W_OFF  = TOTAL * (NB + 1);   // start of W region (elements) = 75497472
constexpr float VRC  = 1.0f / 256.0f;      // VR (exact power of two)

__global__ __launch_bounds__(256) void sar_adc_kernel(
    const float* __restrict__ x,
    const float* __restrict__ W,
    float* __restrict__ out)
{
    // W is uniform across all threads; constant indices -> compiler scalarizes
    // these into s_load + SGPRs.
    float w[36];
#pragma unroll
    for (int i = 0; i < 36; ++i) w[i] = W[i];

    // Third output: copy W through.
    if (blockIdx.x == 0 && threadIdx.x < 36) {
        out[W_OFF + threadIdx.x] = w[threadIdx.x];
    }

    const float4* __restrict__ x4 = (const float4*)x;
    float4* __restrict__ q4 = (float4*)out;
    float4* __restrict__ Q4 = (float4*)(out + Q_OFF);

    const int stride = gridDim.x * blockDim.x;
    for (int v = blockIdx.x * blockDim.x + threadIdx.x; v < NVEC; v += stride) {
        const float4 xv = x4[v];
        const float xe[4] = {xv.x, xv.y, xv.z, xv.w};
        float qout[4];
        float Qb[4][NB];

#pragma unroll
        for (int e = 0; e < 4; ++e) {
            // Work in the x/VR domain: all VR scalings are exact powers of two,
            // so sign decisions are bit-identical to the reference.
            const float xs = xe[e] * 256.0f;
            bool bit[NB];
            int m = 35;
#pragma unroll
            for (int j = NB - 1; j >= 0; --j) {
                float bs = w[m]; m--;            // W[m] * VREF (scaled out)
#pragma unroll
                for (int k = j + 1; k < NB; ++k) {
                    // (Qk+1)/2 in {0,1}: select, then plain add in reference order.
                    // No multiply -> no FMA contraction rounding hazard.
                    bs += bit[k] ? w[m] : 0.0f;
                    m--;
                }
                // sign(diff + 1e-30): diff==0 -> +1; otherwise sign(diff).
                bit[j] = (xs - bs) >= 0.0f;
            }
            int n = 0;
#pragma unroll
            for (int b = 0; b < NB; ++b) {
                Qb[e][b] = bit[b] ? 1.0f : -1.0f;
                n += bit[b] ? (1 << b) : 0;
            }
            qout[e] = (float)n * VRC;            // exact: n <= 255
        }

        q4[v] = make_float4(qout[0], qout[1], qout[2], qout[3]);
#pragma unroll
        for (int t = 0; t < 8; ++t) {
            const int e = t >> 1;
            const int b0 = (t & 1) * 4;
            Q4[(size_t)v * 8 + t] =
                make_float4(Qb[e][b0 + 0], Qb[e][b0 + 1], Qb[e][b0 + 2], Qb[e][b0 + 3]);
        }
    }
}

extern "C" void kernel_launch(void* const* d_in, const int* in_sizes, int n_in,
                              void* d_out, int out_size, void* d_ws, size_t ws_size,
                              hipStream_t stream) {
    const float* x = (const float*)d_in[0];
    const float* W = (const float*)d_in[1];
    float* out = (float*)d_out;

    const int block = 256;
    const int grid = 2048;  // grid-stride, ~8 blocks/CU; 4 iters/thread
    sar_adc_kernel<<<grid, block, 0, stream>>>(x, W, out);
}